// Round 7
// baseline (85.572 us; speedup 1.0000x reference)
//
#include <hip/hip_runtime.h>
#include <hip/hip_bf16.h>

// B=8, T=1024, D=384, K=4
// loss = mean_{b,t,s} exp(-sum_k gt[b,t,s,k]^2/(2 sigma_k^2)) *
//        (||z[b,t]||^2 + ||z[b,s]||^2 - 2 z[b,t].z[b,s])

typedef float  f32x4   __attribute__((ext_vector_type(4)));
typedef short  bf16x8  __attribute__((ext_vector_type(8)));
typedef unsigned short ushort4_t __attribute__((ext_vector_type(4)));

#define T_DIM 1024
#define D_DIM 384

__device__ __forceinline__ unsigned short f32_bf16(float f) {
    unsigned int u = __float_as_uint(f);
    u += 0x7FFFu + ((u >> 16) & 1u);      // RNE
    return (unsigned short)(u >> 16);
}

// ---------------- prep: sq[b*T+t] = sum_d z^2 (exact f32) ----------------
__global__ void prep_sq(const float* __restrict__ z, float* __restrict__ sq) {
    int row  = blockIdx.x;           // 0..8191
    int lane = threadIdx.x;          // 64
    const float* zr = z + (size_t)row * D_DIM;
    float s = 0.f;
#pragma unroll
    for (int q = 0; q < 6; ++q) {
        float x = zr[lane + 64 * q];
        s += x * x;
    }
#pragma unroll
    for (int off = 32; off; off >>= 1) s += __shfl_down(s, off);
    if (lane == 0) sq[row] = s;
}

// ---------------- fused persistent kernel ----------------
// grid 512 = 8 b * 16 t-tiles * 4 s-groups; block 256 (4 waves, each owns 16 t-rows)
// Ping-pong gt register sets (gA/gB): gt(j+1) issued mid-iter j, first
// consumed mid-iter j+1 (stage-z(j+2) vmcnt drain) -> in flight for a full
// iteration, streaming HBM under MFMA(j+1) + barriers. No register copy.
__launch_bounds__(256, 2)
__global__ void tile_loss(const float* __restrict__ z,
                          const float* __restrict__ gt,
                          const float* __restrict__ sigma,
                          const float* __restrict__ sq,
                          float* __restrict__ partials) {
    __shared__ unsigned short Blds[64 * D_DIM];   // 48 KiB, XOR-swizzled rows
    __shared__ float sq_s[T_DIM];                 // 4 KiB: sq[b][:]
    __shared__ float red[4];

    const int bid   = blockIdx.x;                 // 512
    const int b     = bid >> 6;
    const int tt    = (bid >> 2) & 15;
    const int sgrp  = bid & 3;
    const int t0    = tt * 64;
    const int sbase = sgrp * 256;

    const int tid  = threadIdx.x;
    const int lane = tid & 63, w = tid >> 6;
    const int l15  = lane & 15, lq = lane >> 4;

    const float* zb = z + (size_t)b * T_DIM * D_DIM;
    char* bb = (char*)Blds;

    // fold log2(e) into the Gaussian coefficients -> use exp2f
    const float LOG2E = 1.4426950408889634f;
    const float i0 = LOG2E * 0.5f / (sigma[0] * sigma[0]);
    const float i1 = LOG2E * 0.5f / (sigma[1] * sigma[1]);
    const float i2 = LOG2E * 0.5f / (sigma[2] * sigma[2]);
    const float i3 = LOG2E * 0.5f / (sigma[3] * sigma[3]);

    *(float4*)&sq_s[tid * 4] = *(const float4*)&sq[b * T_DIM + tid * 4];

    // ---- A fragments once: row = t0 + w*16 + l15, cols kk*32 + lq*8 .. +8
    bf16x8 af[12];
    {
        const float* Ar = zb + (size_t)(t0 + w * 16 + l15) * D_DIM + lq * 8;
#pragma unroll
        for (int kk = 0; kk < 12; ++kk) {
            float4 lo = *(const float4*)(Ar + kk * 32);
            float4 hi = *(const float4*)(Ar + kk * 32 + 4);
            bf16x8 t;
            t[0] = (short)f32_bf16(lo.x); t[1] = (short)f32_bf16(lo.y);
            t[2] = (short)f32_bf16(lo.z); t[3] = (short)f32_bf16(lo.w);
            t[4] = (short)f32_bf16(hi.x); t[5] = (short)f32_bf16(hi.y);
            t[6] = (short)f32_bf16(hi.z); t[7] = (short)f32_bf16(hi.w);
            af[kk] = t;
        }
    }

    // stage one 64-row B tile (s-rows) into swizzled LDS, f32 -> bf16
    auto stageB = [&](int s0) {
#pragma unroll
        for (int rp = 0; rp < 2; ++rp) {
            int row = rp * 32 + (tid >> 3);
            const float* src = zb + (size_t)(s0 + row) * D_DIM + (tid & 7) * 4;
            int base = row * 768 + (tid & 7) * 8;
            int sw   = (row & 7) << 4;
#pragma unroll
            for (int it = 0; it < 12; ++it) {
                float4 v = *(const float4*)(src + it * 32);
                ushort4_t h = { f32_bf16(v.x), f32_bf16(v.y),
                                f32_bf16(v.z), f32_bf16(v.w) };
                *(ushort4_t*)(bb + ((base + it * 64) ^ sw)) = h;
            }
        }
    };

    const float* gbase = gt + ((size_t)b << 22);  // b*1024*1024*4
    auto loadGT = [&](float4 (&gg)[4][4], int s0) {
#pragma unroll
        for (int nt = 0; nt < 4; ++nt)
#pragma unroll
            for (int r = 0; r < 4; ++r) {
                int t = t0 + w * 16 + lq * 4 + r;
                int s = s0 + nt * 16 + l15;
                gg[nt][r] = *(const float4*)(gbase + (((size_t)t << 10) + s) * 4);
            }
    };

    float psum = 0.f;

    // one pipeline iteration; GCUR consumed by epilogue, GNXT filled for j+1.
    auto iter = [&](int j, float4 (&GCUR)[4][4], float4 (&GNXT)[4][4]) {
        f32x4 acc[4] = {};
#pragma unroll
        for (int kk = 0; kk < 12; ++kk) {
#pragma unroll
            for (int nt = 0; nt < 4; ++nt) {
                int row = nt * 16 + l15;
                int off = (row * 768 + kk * 64 + lq * 16) ^ ((row & 7) << 4);
                bf16x8 bf = *(const bf16x8*)(bb + off);
                acc[nt] = __builtin_amdgcn_mfma_f32_16x16x32_bf16(af[kk], bf, acc[nt], 0, 0, 0);
            }
        }
        __syncthreads();                      // b-frag reads done before restage
        if (j < 3) {
            stageB(sbase + (j + 1) * 64);     // z loads first: their consume drains GCUR (wanted now)
            loadGT(GNXT, sbase + (j + 1) * 64); // stays in flight through epi+sync+MFMA(j+1)
        }
#pragma unroll
        for (int nt = 0; nt < 4; ++nt)
#pragma unroll
            for (int r = 0; r < 4; ++r) {
                int tg2 = t0 + w * 16 + lq * 4 + r;         // C/D: row=(lane>>4)*4+r
                int sg2 = sbase + j * 64 + nt * 16 + l15;   //      col=lane&15
                float d2 = sq_s[tg2] + sq_s[sg2] - 2.0f * acc[nt][r];
                float4 gv = GCUR[nt][r];
                float kv = gv.x * gv.x * i0 + gv.y * gv.y * i1
                         + gv.z * gv.z * i2 + gv.w * gv.w * i3;
                psum += exp2f(-kv) * d2;
            }
        if (j < 3) __syncthreads();           // B(j+1) writes visible before next MFMA
    };

    float4 gA[4][4], gB[4][4];
    stageB(sbase);            // z before gt: no in-order hazard on first tile
    loadGT(gA, sbase);
    __syncthreads();

    iter(0, gA, gB);
    iter(1, gB, gA);
    iter(2, gA, gB);
    iter(3, gB, gA);

#pragma unroll
    for (int off = 32; off; off >>= 1) psum += __shfl_down(psum, off);
    if (lane == 0) red[w] = psum;
    __syncthreads();
    if (tid == 0) partials[bid] = red[0] + red[1] + red[2] + red[3];
}

// ---------------- deterministic final reduction (512 partials) ----------------
__global__ void final_reduce(const float* __restrict__ partials, float* __restrict__ out) {
    __shared__ float red[4];
    int tid = threadIdx.x;  // 256
    float s = partials[tid] + partials[tid + 256];
#pragma unroll
    for (int off = 32; off; off >>= 1) s += __shfl_down(s, off);
    if ((tid & 63) == 0) red[tid >> 6] = s;
    __syncthreads();
    if (tid == 0) out[0] = (red[0] + red[1] + red[2] + red[3]) * (1.0f / 8388608.0f);
}

extern "C" void kernel_launch(void* const* d_in, const int* in_sizes, int n_in,
                              void* d_out, int out_size, void* d_ws, size_t ws_size,
                              hipStream_t stream) {
    const float* z     = (const float*)d_in[0];   // [8,1024,384]
    const float* gt    = (const float*)d_in[1];   // [8,1024,1024,4]
    const float* sigma = (const float*)d_in[2];   // [4]
    float* out = (float*)d_out;

    float* sq       = (float*)d_ws;               // 8192 f32
    float* partials = sq + 8192;                  // 512 f32

    prep_sq<<<8192, 64, 0, stream>>>(z, sq);
    tile_loss<<<512, 256, 0, stream>>>(z, gt, sigma, sq, partials);
    final_reduce<<<1, 256, 0, stream>>>(partials, out);
}

// Round 8
// 82.563 us; speedup vs baseline: 1.0365x; 1.0365x over previous
//
#include <hip/hip_runtime.h>
#include <hip/hip_bf16.h>

// B=8, T=1024, D=384, K=4
// loss = mean_{b,t,s} exp(-sum_k gt[b,t,s,k]^2/(2 sigma_k^2)) *
//        (||z[b,t]||^2 + ||z[b,s]||^2 - 2 z[b,t].z[b,s])
//
// Two-phase design: phase 1 (gram_d2) computes dist2 -> bf16 in ws (no gt);
// phase 2 (stream_loss) is a pure barrier-free stream over gt + d2.

typedef float  f32x4   __attribute__((ext_vector_type(4)));
typedef short  bf16x8  __attribute__((ext_vector_type(8)));
typedef unsigned short ushort4_t __attribute__((ext_vector_type(4)));

#define T_DIM 1024
#define D_DIM 384

__device__ __forceinline__ unsigned short f32_bf16(float f) {
    unsigned int u = __float_as_uint(f);
    u += 0x7FFFu + ((u >> 16) & 1u);      // RNE
    return (unsigned short)(u >> 16);
}

// ---------------- prep: sq[b*T+t] = sum_d z^2 (exact f32) ----------------
__global__ void prep_sq(const float* __restrict__ z, float* __restrict__ sq) {
    int row  = blockIdx.x;           // 0..8191
    int lane = threadIdx.x;          // 64
    const float* zr = z + (size_t)row * D_DIM;
    float s = 0.f;
#pragma unroll
    for (int q = 0; q < 6; ++q) {
        float x = zr[lane + 64 * q];
        s += x * x;
    }
#pragma unroll
    for (int off = 32; off; off >>= 1) s += __shfl_down(s, off);
    if (lane == 0) sq[row] = s;
}

// ---------------- phase 1: dist2 tile -> bf16 (no gt) ----------------
// grid 512 = 8 b * 16 t-tiles * 4 s-groups; block 256 (4 waves x 16 t-rows).
// A-frags register-resident; B staged per 64-s-tile in swizzled LDS.
__launch_bounds__(256, 2)
__global__ void gram_d2(const float* __restrict__ z,
                        const float* __restrict__ sq,
                        unsigned short* __restrict__ d2w) {
    __shared__ unsigned short Blds[64 * D_DIM];   // 48 KiB, XOR-swizzled rows
    __shared__ float sq_s[T_DIM];                 // 4 KiB

    const int bid   = blockIdx.x;                 // 512
    const int b     = bid >> 6;
    const int tt    = (bid >> 2) & 15;
    const int sgrp  = bid & 3;
    const int t0    = tt * 64;
    const int sbase = sgrp * 256;

    const int tid  = threadIdx.x;
    const int lane = tid & 63, w = tid >> 6;
    const int l15  = lane & 15, lq = lane >> 4;

    const float* zb = z + (size_t)b * T_DIM * D_DIM;
    char* bb = (char*)Blds;

    *(float4*)&sq_s[tid * 4] = *(const float4*)&sq[b * T_DIM + tid * 4];

    // A fragments once: row = t0 + w*16 + l15, cols kk*32 + lq*8 .. +8
    bf16x8 af[12];
    {
        const float* Ar = zb + (size_t)(t0 + w * 16 + l15) * D_DIM + lq * 8;
#pragma unroll
        for (int kk = 0; kk < 12; ++kk) {
            float4 lo = *(const float4*)(Ar + kk * 32);
            float4 hi = *(const float4*)(Ar + kk * 32 + 4);
            bf16x8 t;
            t[0] = (short)f32_bf16(lo.x); t[1] = (short)f32_bf16(lo.y);
            t[2] = (short)f32_bf16(lo.z); t[3] = (short)f32_bf16(lo.w);
            t[4] = (short)f32_bf16(hi.x); t[5] = (short)f32_bf16(hi.y);
            t[6] = (short)f32_bf16(hi.z); t[7] = (short)f32_bf16(hi.w);
            af[kk] = t;
        }
    }

    for (int j = 0; j < 4; ++j) {
        const int s0 = sbase + j * 64;
        // stage 64-row B tile, f32 -> bf16, XOR-swizzled
#pragma unroll
        for (int rp = 0; rp < 2; ++rp) {
            int row = rp * 32 + (tid >> 3);
            const float* src = zb + (size_t)(s0 + row) * D_DIM + (tid & 7) * 4;
            int base = row * 768 + (tid & 7) * 8;
            int sw   = (row & 7) << 4;
#pragma unroll
            for (int it = 0; it < 12; ++it) {
                float4 v = *(const float4*)(src + it * 32);
                ushort4_t h = { f32_bf16(v.x), f32_bf16(v.y),
                                f32_bf16(v.z), f32_bf16(v.w) };
                *(ushort4_t*)(bb + ((base + it * 64) ^ sw)) = h;
            }
        }
        __syncthreads();

        f32x4 acc[4] = {};
#pragma unroll
        for (int kk = 0; kk < 12; ++kk) {
#pragma unroll
            for (int nt = 0; nt < 4; ++nt) {
                int row = nt * 16 + l15;
                int off = (row * 768 + kk * 64 + lq * 16) ^ ((row & 7) << 4);
                bf16x8 bf = *(const bf16x8*)(bb + off);
                acc[nt] = __builtin_amdgcn_mfma_f32_16x16x32_bf16(af[kk], bf, acc[nt], 0, 0, 0);
            }
        }
        __syncthreads();   // B reads done before next-j restage

        // epilogue: d2 = sqA + sqB - 2*gram -> bf16 store (row-major [t][s])
        // C/D layout: col = lane&15 (s), row = (lane>>4)*4 + r (t)
#pragma unroll
        for (int nt = 0; nt < 4; ++nt)
#pragma unroll
            for (int r = 0; r < 4; ++r) {
                int t = t0 + w * 16 + lq * 4 + r;
                int s = s0 + nt * 16 + l15;
                float d2 = sq_s[t] + sq_s[s] - 2.0f * acc[nt][r];
                d2w[((size_t)b << 20) + ((size_t)t << 10) + s] = f32_bf16(d2);
            }
    }
}

// ---------------- phase 2: pure stream over gt + d2 ----------------
// 2048 blocks x 256 threads; element e = (b,t,s); 16 elements/thread.
// No barriers, no LDS in loop -> TLP saturates HBM.
__launch_bounds__(256, 4)
__global__ void stream_loss(const float* __restrict__ gt,
                            const unsigned short* __restrict__ d2w,
                            const float* __restrict__ sigma,
                            float* __restrict__ partials) {
    __shared__ float red[4];
    const float LOG2E = 1.4426950408889634f;
    const float i0 = LOG2E * 0.5f / (sigma[0] * sigma[0]);
    const float i1 = LOG2E * 0.5f / (sigma[1] * sigma[1]);
    const float i2 = LOG2E * 0.5f / (sigma[2] * sigma[2]);
    const float i3 = LOG2E * 0.5f / (sigma[3] * sigma[3]);

    const int gtid = blockIdx.x * 256 + threadIdx.x;   // 524288 threads
    const float4* gt4 = (const float4*)gt;

    float acc = 0.f;
#pragma unroll 4
    for (int g2 = 0; g2 < 16; ++g2) {
        size_t e = (size_t)g2 * 524288 + gtid;         // coalesced: 16 B/lane
        float4 gv = gt4[e];
        float dd = __uint_as_float(((unsigned)d2w[e]) << 16);
        float kv = gv.x * gv.x * i0 + gv.y * gv.y * i1
                 + gv.z * gv.z * i2 + gv.w * gv.w * i3;
        acc += exp2f(-kv) * dd;
    }

    int lane = threadIdx.x & 63, w = threadIdx.x >> 6;
#pragma unroll
    for (int off = 32; off; off >>= 1) acc += __shfl_down(acc, off);
    if (lane == 0) red[w] = acc;
    __syncthreads();
    if (threadIdx.x == 0) partials[blockIdx.x] = red[0] + red[1] + red[2] + red[3];
}

// ---------------- deterministic final reduction (2048 partials) ----------------
__global__ void final_reduce(const float* __restrict__ partials, float* __restrict__ out) {
    __shared__ float red[4];
    int tid = threadIdx.x;  // 256
    float s = 0.f;
    for (int i = tid; i < 2048; i += 256) s += partials[i];
#pragma unroll
    for (int off = 32; off; off >>= 1) s += __shfl_down(s, off);
    if ((tid & 63) == 0) red[tid >> 6] = s;
    __syncthreads();
    if (tid == 0) out[0] = (red[0] + red[1] + red[2] + red[3]) * (1.0f / 8388608.0f);
}

extern "C" void kernel_launch(void* const* d_in, const int* in_sizes, int n_in,
                              void* d_out, int out_size, void* d_ws, size_t ws_size,
                              hipStream_t stream) {
    const float* z     = (const float*)d_in[0];   // [8,1024,384]
    const float* gt    = (const float*)d_in[1];   // [8,1024,1024,4]
    const float* sigma = (const float*)d_in[2];   // [4]
    float* out = (float*)d_out;

    float* sq            = (float*)d_ws;                    // 8192 f32
    float* partials      = sq + 8192;                       // 2048 f32
    unsigned short* d2w  = (unsigned short*)(sq + 10240);   // 8.4M bf16 = 16.8 MB

    prep_sq<<<8192, 64, 0, stream>>>(z, sq);
    gram_d2<<<512, 256, 0, stream>>>(z, sq, d2w);
    stream_loss<<<2048, 256, 0, stream>>>(gt, d2w, sigma, partials);
    final_reduce<<<1, 256, 0, stream>>>(partials, out);
}